// Round 9
// baseline (751.408 us; speedup 1.0000x reference)
//
#include <hip/hip_runtime.h>

#define CH 256
#define KC 8192
#define NT 32768

#define TPW 32         // tokens per wave (A panel in VGPRs)
#define JT  64         // codes per jt tile
#define JTS 64         // jt tiles per block (4096-code half)

typedef _Float16 half4_t __attribute__((ext_vector_type(4)));
typedef _Float16 half8_t __attribute__((ext_vector_type(8)));
typedef float floatx16 __attribute__((ext_vector_type(16)));

typedef __attribute__((address_space(1))) const unsigned int guint_t;
typedef __attribute__((address_space(3))) unsigned int luint_t;

// ---------------------------------------------------------------------------
// Kernel 1 (fused prep):
//  blocks [0, KC):   codebook row -> fp16 hi/lo + cbsq, zero hist, init packed
//  blocks [KC, ...): split embeddings fp32 -> fp16 hi/lo (1 float4/thread)
// ---------------------------------------------------------------------------
__global__ void k_prep(const float* __restrict__ usage,
                       const float* __restrict__ ces,
                       const float* __restrict__ emb,
                       _Float16* __restrict__ cbh,
                       _Float16* __restrict__ cbl,
                       float* __restrict__ cbsq,
                       _Float16* __restrict__ eh,
                       _Float16* __restrict__ el,
                       int* __restrict__ hist,
                       unsigned long long* __restrict__ packed) {
    int b = blockIdx.x, t = threadIdx.x;
    if (b < KC) {
        float uc = fmaxf(usage[b], 1e-5f);
        float v  = ces[b * CH + t];
        float cb = v / uc;
        _Float16 h = (_Float16)cb;
        cbh[b * CH + t] = h;
        cbl[b * CH + t] = (_Float16)(cb - (float)h);

        float p = cb * cb;
        #pragma unroll
        for (int off = 32; off; off >>= 1) p += __shfl_down(p, off);
        __shared__ float ps[4];
        int lane = t & 63, w = t >> 6;
        if (lane == 0) ps[w] = p;
        __syncthreads();
        if (t == 0) cbsq[b] = ps[0] + ps[1] + ps[2] + ps[3];
        if (t == 1) hist[b] = 0;
        int gid = b * CH + t;
        if (gid < NT) packed[gid] = 0xFFFFFFFFFFFFFFFFull;
    } else {
        int i = (b - KC) * 256 + t;      // float4 index
        float4 v = ((const float4*)emb)[i];
        float va[4] = {v.x, v.y, v.z, v.w};
        half4_t h, l;
        #pragma unroll
        for (int q = 0; q < 4; ++q) {
            _Float16 hh = (_Float16)va[q];
            h[q] = hh;
            l[q] = (_Float16)(va[q] - (float)hh);
        }
        ((half4_t*)eh)[i] = h;
        ((half4_t*)el)[i] = l;
    }
}

// ---------------------------------------------------------------------------
// Kernel 2: fp16-split argmin — B-lo off the LDS pipe.
// Round-7/8 skeleton, but per k-step the wave now does only TWO ds_read_b128
// (B-hi fragments, double-buffered regs, read 1 step ahead) while the B-lo
// fragments come STRAIGHT FROM GLOBAL (L2/L1) into a 4-set rotating register
// buffer issued 2 steps ahead (16 steps % 4 == 0 -> all indices static).
// Per-CU per-step: LDS 16 reads x 12 = 192 cyc << MFMA 387 cyc -> LDS pipe
// fully hidden; B-lo = 16 KB/CU/step from L2 (~42 B/cyc, lines re-hit in L1).
// LDS B-hi: 32 KB/jt, double-buffered (64 KiB total), one barrier per jt.
// A panel (32 tok, hi+lo) in 128 VGPRs; 32x32x16 MFMA; atomicMin merge.
// ---------------------------------------------------------------------------
__launch_bounds__(512, 2)
__global__ void k_argmin(const _Float16* __restrict__ eh,
                         const _Float16* __restrict__ el,
                         const _Float16* __restrict__ cbh,
                         const _Float16* __restrict__ cbl,
                         const float* __restrict__ cbsq,
                         unsigned long long* __restrict__ packed) {
    __shared__ __align__(16) char smB[65536];   // 2 x 32 KiB B-hi dbuf

    const int t    = threadIdx.x;
    const int lane = t & 63;
    const int wave = t >> 6;          // 0..7: token group
    const int lr32 = lane & 31;       // fragment row/col
    const int kh   = lane >> 5;       // 8-ch half within a 16-ch k-step

    const int n0w = blockIdx.x * 256 + wave * TPW;   // this wave's tokens
    const int jq  = blockIdx.y * (JTS * JT);         // code half base

    // ---- A panel -> registers (once). lane holds row lr32,
    // halves ch = ks*16 + kh*8 .. +7; 16 k-steps x hi/lo.
    half8_t aregh[16], aregl[16];
    {
        const size_t rowoff = (size_t)(n0w + lr32) * CH + kh * 8;
        #pragma unroll
        for (int ks = 0; ks < 16; ++ks) {
            aregh[ks] = *(const half8_t*)(eh + rowoff + ks * 16);
            aregl[ks] = *(const half8_t*)(el + rowoff + ks * 16);
        }
    }

    // ---- B-hi jt-tile DMA: 4 x 1KB issues/wave; wave w stages ks = w*2 +
    // (d>>1), sub-half = d&1. Lane l -> code l (layout [ks][sub][code]x16B).
    auto dmaB = [&](int buf, int jt) {
        const int jb = jq + jt * JT;
        #pragma unroll
        for (int d = 0; d < 4; ++d) {
            const int ks  = wave * 2 + (d >> 1);
            const int sub = d & 1;
            const _Float16* g = cbh + (size_t)(jb + lane) * CH
                              + ks * 16 + sub * 8;
            __builtin_amdgcn_global_load_lds(
                (guint_t*)g,
                (luint_t*)(smB + buf * 32768 + ks * 2048 + sub * 1024),
                16, 0, 0);
        }
    };

    float minv[16];
    int   mini[16];
    #pragma unroll
    for (int e = 0; e < 16; ++e) { minv[e] = 3.402823466e38f; mini[e] = 0; }

    floatx16 acc0, acc1;
    #pragma unroll
    for (int r = 0; r < 16; ++r) { acc0[r] = 0.f; acc1[r] = 0.f; }

    // rotating register buffers (all names static)
    half8_t HA0, HA1, HB0, HB1;                   // B-hi, 2 sets
    half8_t LA0, LA1, LB0, LB1, LC0, LC1, LD0, LD1;   // B-lo, 4 sets

    // B-lo global fragment issue: codes (JBX + nf*32 + lr32), ch KS*16+kh*8
#define LO_ISSUE(KS2, JBX, L)                                                \
    { const _Float16* g_ = cbl + (size_t)((JBX) + lr32) * CH                 \
                         + (KS2) * 16 + kh * 8;                              \
      L##0 = *(const half8_t*)g_;                                           \
      L##1 = *(const half8_t*)(g_ + 32 * CH); }

#define HI_READ(KS1, H)                                                      \
    { const char* bp_ = bbase + (KS1) * 2048;                                \
      H##0 = *(const half8_t*)bp_;                                          \
      H##1 = *(const half8_t*)(bp_ + 512); }

#define MFMA6(KS, H, L)                                                      \
    acc0 = __builtin_amdgcn_mfma_f32_32x32x16_f16(aregh[KS], H##0, acc0, 0,0,0); \
    acc1 = __builtin_amdgcn_mfma_f32_32x32x16_f16(aregh[KS], H##1, acc1, 0,0,0); \
    acc0 = __builtin_amdgcn_mfma_f32_32x32x16_f16(aregh[KS], L##0, acc0, 0,0,0); \
    acc1 = __builtin_amdgcn_mfma_f32_32x32x16_f16(aregh[KS], L##1, acc1, 0,0,0); \
    acc0 = __builtin_amdgcn_mfma_f32_32x32x16_f16(aregl[KS], H##0, acc0, 0,0,0); \
    acc1 = __builtin_amdgcn_mfma_f32_32x32x16_f16(aregl[KS], H##1, acc1, 0,0,0);

    // prologue: B-hi jt0 -> buf0; B-lo steps 0,1 -> LA,LB
    dmaB(0, 0);
    LO_ISSUE(0, jq, LA)
    LO_ISSUE(1, jq, LB)
    __syncthreads();

    #pragma unroll 1
    for (int jt = 0; jt < JTS; ++jt) {
        const int buf = jt & 1;
        const int jb  = jq + jt * JT;
        const int jb2 = (jt + 1 < JTS) ? jb + JT : jb;   // next jt (clamped)

        // prefetch next jt's B-hi into the other buffer
        if (jt + 1 < JTS) dmaB(buf ^ 1, jt + 1);

        // cbsq for this jt (in flight over the whole jt)
        const float csq0 = cbsq[jb + lr32];
        const float csq1 = cbsq[jb + 32 + lr32];

        const char* bbase = smB + buf * 32768 + kh * 1024 + lr32 * 16;

        HI_READ(0, HA)
        // step KS: issue lo(KS+2), read hi(KS+1), MFMA6(KS)
        LO_ISSUE(2,  jb,  LC) HI_READ(1,  HB) MFMA6(0,  HA, LA)
        LO_ISSUE(3,  jb,  LD) HI_READ(2,  HA) MFMA6(1,  HB, LB)
        LO_ISSUE(4,  jb,  LA) HI_READ(3,  HB) MFMA6(2,  HA, LC)
        LO_ISSUE(5,  jb,  LB) HI_READ(4,  HA) MFMA6(3,  HB, LD)
        LO_ISSUE(6,  jb,  LC) HI_READ(5,  HB) MFMA6(4,  HA, LA)
        LO_ISSUE(7,  jb,  LD) HI_READ(6,  HA) MFMA6(5,  HB, LB)
        LO_ISSUE(8,  jb,  LA) HI_READ(7,  HB) MFMA6(6,  HA, LC)
        LO_ISSUE(9,  jb,  LB) HI_READ(8,  HA) MFMA6(7,  HB, LD)
        LO_ISSUE(10, jb,  LC) HI_READ(9,  HB) MFMA6(8,  HA, LA)
        LO_ISSUE(11, jb,  LD) HI_READ(10, HA) MFMA6(9,  HB, LB)
        LO_ISSUE(12, jb,  LA) HI_READ(11, HB) MFMA6(10, HA, LC)
        LO_ISSUE(13, jb,  LB) HI_READ(12, HA) MFMA6(11, HB, LD)
        LO_ISSUE(14, jb,  LC) HI_READ(13, HB) MFMA6(12, HA, LA)
        LO_ISSUE(15, jb,  LD) HI_READ(14, HA) MFMA6(13, HB, LB)
        LO_ISSUE(0,  jb2, LA) HI_READ(15, HB) MFMA6(14, HA, LC)
        LO_ISSUE(1,  jb2, LB)                 MFMA6(15, HB, LD)

        // ---- fold: d2 = cbsq - 2*dot. C layout (validated):
        // col = jb + nf*32 + lr32, row = (r&3) + 8*(r>>2) + 4*kh.
        #pragma unroll
        for (int r = 0; r < 16; ++r) {
            float s0 = csq0 - 2.0f * acc0[r];
            float s1 = csq1 - 2.0f * acc1[r];
            float sv = s0; int si = jb + lr32;
            if (s1 < sv) { sv = s1; si = jb + 32 + lr32; }
            if (sv < minv[r]) { minv[r] = sv; mini[r] = si; }
            acc0[r] = 0.f;
            acc1[r] = 0.f;
        }

        // jt rendezvous: drains my DMA + all waves' hi reads of buf
        __syncthreads();
    }
#undef MFMA6
#undef HI_READ
#undef LO_ISSUE

    // ---- epilogue: reduce over the 32 codes held across lanes (lr32),
    // then atomicMin into packed (cross-code-half merge).
    #pragma unroll
    for (int r = 0; r < 16; ++r) {
        float v = minv[r];
        int   x = mini[r];
        #pragma unroll
        for (int m = 1; m <= 16; m <<= 1) {
            float ov = __shfl_xor(v, m, 64);
            int   ox = __shfl_xor(x, m, 64);
            if (ov < v || (ov == v && ox < x)) { v = ov; x = ox; }
        }
        if (lr32 == 0) {    // lanes 0 (kh=0) and 32 (kh=1)
            int tok = n0w + (r & 3) + 8 * (r >> 2) + 4 * kh;
            unsigned sb = __float_as_uint(v);
            sb = (sb & 0x80000000u) ? ~sb : (sb | 0x80000000u);
            unsigned long long key =
                ((unsigned long long)sb << 32) | (unsigned)x;
            atomicMin(&packed[tok], key);
        }
    }
}

// ---------------------------------------------------------------------------
// Kernel 3: gather + straight-through + loss partials + histogram
// ---------------------------------------------------------------------------
__global__ void k_gather(const float* __restrict__ emb,
                         const float* __restrict__ ces,
                         const float* __restrict__ usage,
                         const unsigned long long* __restrict__ packed,
                         float* __restrict__ out_eq,
                         float* __restrict__ codes_f,
                         int* __restrict__ hist,
                         float* __restrict__ partials) {
    int t = threadIdx.x;
    int wave = t >> 6, lane = t & 63;
    int n = blockIdx.x * 4 + wave;
    int k = (int)(packed[n] & 0xFFFFFFFFull);
    float uc = fmaxf(usage[k], 1e-5f);
    int c = lane * 4;

    float4 e = *(const float4*)&emb[(size_t)n * CH + c];
    float4 v = *(const float4*)&ces[(size_t)k * CH + c];
    float ea[4] = {e.x, e.y, e.z, e.w};
    float va[4] = {v.x, v.y, v.z, v.w};
    float eqa[4];
    float p = 0.0f;
    #pragma unroll
    for (int q = 0; q < 4; ++q) {
        float cb = va[q] / uc;
        float eq = ea[q] + (cb - ea[q]);
        eqa[q] = eq;
        float d = eq - ea[q];
        p += d * d;
    }
    *(float4*)&out_eq[(size_t)n * CH + c] =
        (float4){eqa[0], eqa[1], eqa[2], eqa[3]};

    #pragma unroll
    for (int off = 32; off; off >>= 1) p += __shfl_down(p, off);
    __shared__ float ps[4];
    if (lane == 0) {
        ps[wave] = p;
        codes_f[n] = (float)k;
        atomicAdd(&hist[k], 1);
    }
    __syncthreads();
    if (t == 0) partials[blockIdx.x] = ps[0] + ps[1] + ps[2] + ps[3];
}

// ---------------------------------------------------------------------------
// Kernel 4: exclusive prefix sum over hist -> offs, cursor (1 block)
// ---------------------------------------------------------------------------
__global__ void k_scan(const int* __restrict__ hist,
                       int* __restrict__ offs,
                       int* __restrict__ cursor) {
    __shared__ int bs[256];
    int t = threadIdx.x;
    int base = t * 32;
    int loc[32];
    int s = 0;
    #pragma unroll
    for (int i = 0; i < 32; ++i) { loc[i] = s; s += hist[base + i]; }
    int mysum = s;
    bs[t] = s;
    __syncthreads();
    for (int off = 1; off < 256; off <<= 1) {
        int v = (t >= off) ? bs[t - off] : 0;
        __syncthreads();
        bs[t] += v;
        __syncthreads();
    }
    int excl = bs[t] - mysum;
    #pragma unroll
    for (int i = 0; i < 32; ++i) {
        int o = excl + loc[i];
        offs[base + i]   = o;
        cursor[base + i] = o;
    }
}

// ---------------------------------------------------------------------------
// Kernel 5: scatter token ids into code-sorted buckets
// ---------------------------------------------------------------------------
__global__ void k_scatter(const unsigned long long* __restrict__ packed,
                          int* __restrict__ cursor,
                          int* __restrict__ bucket) {
    int n = blockIdx.x * 256 + threadIdx.x;
    int k = (int)(packed[n] & 0xFFFFFFFFull);
    int pos = atomicAdd(&cursor[k], 1);
    bucket[pos] = n;
}

// ---------------------------------------------------------------------------
// Kernel 6: per-code EMA (one BLOCK per code: coalesced 1KB row loads,
// thread t owns channel t, no atomics, no wave-serial latency chain)
// ---------------------------------------------------------------------------
__global__ void k_ema(const float* __restrict__ emb,
                      const float* __restrict__ ces,
                      const float* __restrict__ usage,
                      const int* __restrict__ hist,
                      const int* __restrict__ offs,
                      const int* __restrict__ bucket,
                      float* __restrict__ out_ces,
                      float* __restrict__ out_usage) {
    const float s = 0.01f;
    const float oms = 1.0f - s;
    int k = blockIdx.x, t = threadIdx.x;
    int start = offs[k], cnt = hist[k];
    float sum = 0.0f;
    #pragma unroll 2
    for (int i = 0; i < cnt; ++i) {
        int n = bucket[start + i];            // block-uniform (scalar) load
        sum += emb[(size_t)n * CH + t];       // coalesced row
    }
    out_ces[(size_t)k * CH + t] = oms * ces[(size_t)k * CH + t] + s * sum;
    if (t == 0) out_usage[k] = oms * usage[k] + s * (float)cnt;
}

// ---------------------------------------------------------------------------
// Kernel 7: reduce loss partials, mean over 2^23 elements
// ---------------------------------------------------------------------------
__global__ void k_final(const float* __restrict__ partials,
                        float* __restrict__ out_loss) {
    int t = threadIdx.x;
    float p = 0.0f;
    for (int i = t; i < NT / 4; i += 256) p += partials[i];
    #pragma unroll
    for (int off = 32; off; off >>= 1) p += __shfl_down(p, off);
    __shared__ float ps[4];
    if ((t & 63) == 0) ps[t >> 6] = p;
    __syncthreads();
    if (t == 0)
        out_loss[0] = (ps[0] + ps[1] + ps[2] + ps[3]) * (1.0f / 8388608.0f);
}

extern "C" void kernel_launch(void* const* d_in, const int* in_sizes, int n_in,
                              void* d_out, int out_size, void* d_ws, size_t ws_size,
                              hipStream_t stream) {
    const float* emb   = (const float*)d_in[0];  // [32768, 256]
    const float* usage = (const float*)d_in[1];  // [8192]
    const float* ces   = (const float*)d_in[2];  // [8192, 256]

    float* out      = (float*)d_out;
    float* o_codes  = out;                       // 32768
    float* o_eq     = out + NT;                  // 8388608
    float* o_loss   = o_eq + (size_t)NT * CH;    // 1
    float* o_usage  = o_loss + 1;                // 8192
    float* o_ces    = o_usage + KC;              // 2097152

    unsigned long long* packed = (unsigned long long*)d_ws;   // NT u64
    float* cbsq     = (float*)(packed + NT);                  // KC
    float* partials = cbsq + KC;                              // NT/4
    int* hist   = (int*)(partials + NT / 4);                  // KC
    int* offs   = hist + KC;                                  // KC
    int* cursor = offs + KC;                                  // KC
    int* bucket = cursor + KC;                                // NT
    _Float16* eh  = (_Float16*)(bucket + NT);                 // NT*CH
    _Float16* el  = eh + (size_t)NT * CH;
    _Float16* cbh = el + (size_t)NT * CH;                     // KC*CH
    _Float16* cbl = cbh + (size_t)KC * CH;

    k_prep<<<KC + NT * CH / 1024, 256, 0, stream>>>(
        usage, ces, emb, cbh, cbl, cbsq, eh, el, hist, packed);
    dim3 agrid(NT / 256, 2);
    k_argmin<<<agrid, 512, 0, stream>>>(eh, el, cbh, cbl, cbsq, packed);
    k_gather<<<NT / 4, 256, 0, stream>>>(emb, ces, usage, packed, o_eq,
                                         o_codes, hist, partials);
    k_scan<<<1, 256, 0, stream>>>(hist, offs, cursor);
    k_scatter<<<NT / 256, 256, 0, stream>>>(packed, cursor, bucket);
    k_ema<<<KC, 256, 0, stream>>>(emb, ces, usage, hist, offs, bucket,
                                  o_ces, o_usage);
    k_final<<<1, 256, 0, stream>>>(partials, o_loss);
}

// Round 10
// 649.072 us; speedup vs baseline: 1.1577x; 1.1577x over previous
//
#include <hip/hip_runtime.h>

#define CH 256
#define KC 8192
#define NT 32768

#define TPW 64         // tokens per wave (2 A-fragments in VGPRs)
#define JT  64         // codes per jt tile
#define JTS 64         // jt tiles per block (4096-code half)

typedef _Float16 half4_t __attribute__((ext_vector_type(4)));
typedef _Float16 half8_t __attribute__((ext_vector_type(8)));
typedef float floatx16 __attribute__((ext_vector_type(16)));

typedef __attribute__((address_space(1))) const unsigned int guint_t;
typedef __attribute__((address_space(3))) unsigned int luint_t;

// ---------------------------------------------------------------------------
// Kernel 1 (fused prep):
//  blocks [0, KC):   codebook row -> fp16 hi/lo + cbsq, zero hist, init packed
//  blocks [KC, ...): split embeddings fp32 -> fp16 hi/lo (1 float4/thread)
// ---------------------------------------------------------------------------
__global__ void k_prep(const float* __restrict__ usage,
                       const float* __restrict__ ces,
                       const float* __restrict__ emb,
                       _Float16* __restrict__ cbh,
                       _Float16* __restrict__ cbl,
                       float* __restrict__ cbsq,
                       _Float16* __restrict__ eh,
                       _Float16* __restrict__ el,
                       int* __restrict__ hist,
                       unsigned long long* __restrict__ packed) {
    int b = blockIdx.x, t = threadIdx.x;
    if (b < KC) {
        float uc = fmaxf(usage[b], 1e-5f);
        float v  = ces[b * CH + t];
        float cb = v / uc;
        _Float16 h = (_Float16)cb;
        cbh[b * CH + t] = h;
        cbl[b * CH + t] = (_Float16)(cb - (float)h);

        float p = cb * cb;
        #pragma unroll
        for (int off = 32; off; off >>= 1) p += __shfl_down(p, off);
        __shared__ float ps[4];
        int lane = t & 63, w = t >> 6;
        if (lane == 0) ps[w] = p;
        __syncthreads();
        if (t == 0) cbsq[b] = ps[0] + ps[1] + ps[2] + ps[3];
        if (t == 1) hist[b] = 0;
        int gid = b * CH + t;
        if (gid < NT) packed[gid] = 0xFFFFFFFFFFFFFFFFull;
    } else {
        int i = (b - KC) * 256 + t;      // float4 index
        float4 v = ((const float4*)emb)[i];
        float va[4] = {v.x, v.y, v.z, v.w};
        half4_t h, l;
        #pragma unroll
        for (int q = 0; q < 4; ++q) {
            _Float16 hh = (_Float16)va[q];
            h[q] = hh;
            l[q] = (_Float16)(va[q] - (float)hh);
        }
        ((half4_t*)eh)[i] = h;
        ((half4_t*)el)[i] = l;
    }
}

// ---------------------------------------------------------------------------
// Kernel 2: fp16-split argmin — nA=2: 64 tokens/wave, halved B traffic/MFMA.
// 4 waves/block (256 thr, 1 wave/SIMD), wave owns 64 tokens: TWO 32x32
// A-fragment rows, hi+lo, fully in VGPRs (~256 regs; launch_bounds(256,1)).
// B machinery is round-7's proven path UNCHANGED: k-major LDS layout
// [ks][h][sub][code]x16B (measured 0 conflicts), global_load_lds DMA,
// 2 x 64 KiB double buffer, ONE barrier per jt. Per CU per k-step:
// 16 ds_read_b128 (192 cyc) vs 48 MFMA (387 cyc) -> LDS pipe has 2x slack
// and hides under the matrix pipe; matrix pipe is the only saturated
// resource. B-fragment register double-buffer (p/q sets) prefetches step
// ks+1 before ks's 12 MFMA. 4 independent acc chains (dep distance 4 MFMA).
// Cross-code-half merge via packed-u64 atomicMin (proven).
// ---------------------------------------------------------------------------
__launch_bounds__(256, 1)
__global__ void k_argmin(const _Float16* __restrict__ eh,
                         const _Float16* __restrict__ el,
                         const _Float16* __restrict__ cbh,
                         const _Float16* __restrict__ cbl,
                         const float* __restrict__ cbsq,
                         unsigned long long* __restrict__ packed) {
    __shared__ __align__(16) char smB[131072];   // 2 x 64 KiB B dbuf

    const int t    = threadIdx.x;
    const int lane = t & 63;
    const int wave = t >> 6;          // 0..3: token group (64 tokens)
    const int lr32 = lane & 31;       // fragment row/col
    const int kh   = lane >> 5;       // 8-ch half within a 16-ch k-step

    const int n0w = blockIdx.x * 256 + wave * TPW;   // this wave's tokens
    const int jq  = blockIdx.y * (JTS * JT);         // code half base

    // ---- A panel -> registers (once). Two fragments (m=0: rows lr32,
    // m=1: rows 32+lr32), each: ch = ks*16 + kh*8 .. +7, 16 k-steps, hi+lo.
    half8_t a0h[16], a0l[16], a1h[16], a1l[16];
    {
        const size_t ro0 = (size_t)(n0w + lr32) * CH + kh * 8;
        const size_t ro1 = ro0 + (size_t)32 * CH;
        #pragma unroll
        for (int ks = 0; ks < 16; ++ks) {
            a0h[ks] = *(const half8_t*)(eh + ro0 + ks * 16);
            a0l[ks] = *(const half8_t*)(el + ro0 + ks * 16);
            a1h[ks] = *(const half8_t*)(eh + ro1 + ks * 16);
            a1l[ks] = *(const half8_t*)(el + ro1 + ks * 16);
        }
    }

    // ---- B jt-tile DMA: 16 x 1KB issues/wave (4 waves cover 64 KiB).
    // Wave w stages planes p = w*8 + (d>>1): ks = p>>1, h = p&1, sub = d&1.
    // Lane l -> code l. Layout [ks][h][sub][code]x16B (round-7 proven).
    auto dmaB = [&](int buf, int jt) {
        const int jb = jq + jt * JT;
        #pragma unroll
        for (int d = 0; d < 16; ++d) {
            const int p   = wave * 8 + (d >> 1);   // plane 0..31
            const int ks  = p >> 1;
            const int h   = p & 1;
            const int sub = d & 1;
            const _Float16* src = h ? cbl : cbh;
            const _Float16* g = src + (size_t)(jb + lane) * CH
                              + ks * 16 + sub * 8;
            __builtin_amdgcn_global_load_lds(
                (guint_t*)g,
                (luint_t*)(smB + buf * 65536 + ks * 4096 + h * 2048
                           + sub * 1024),
                16, 0, 0);
        }
    };

    float minv[32];
    int   mini[32];
    #pragma unroll
    for (int e = 0; e < 32; ++e) { minv[e] = 3.402823466e38f; mini[e] = 0; }

    floatx16 acc00, acc01, acc10, acc11;
    #pragma unroll
    for (int r = 0; r < 16; ++r) {
        acc00[r] = 0.f; acc01[r] = 0.f; acc10[r] = 0.f; acc11[r] = 0.f;
    }

    // prologue: jt 0 -> buf 0
    dmaB(0, 0);
    __syncthreads();

    // per-lane B fragment slot: [kh][code] -> byte (kh*64 + lr32)*16
    const int lslot = (kh * 64 + lr32) * 16;

#define PRIME(KS, R)                                                         \
    { const char* bp_ = bbase + (KS) * 4096;                                 \
      R##0 = *(const half8_t*)(bp_);                                         \
      R##1 = *(const half8_t*)(bp_ + 512);                                   \
      R##2 = *(const half8_t*)(bp_ + 2048);                                  \
      R##3 = *(const half8_t*)(bp_ + 2560); }

#define MFMA12(KS, B)                                                        \
    acc00 = __builtin_amdgcn_mfma_f32_32x32x16_f16(a0h[KS], B##0, acc00, 0,0,0); \
    acc01 = __builtin_amdgcn_mfma_f32_32x32x16_f16(a0h[KS], B##1, acc01, 0,0,0); \
    acc10 = __builtin_amdgcn_mfma_f32_32x32x16_f16(a1h[KS], B##0, acc10, 0,0,0); \
    acc11 = __builtin_amdgcn_mfma_f32_32x32x16_f16(a1h[KS], B##1, acc11, 0,0,0); \
    acc00 = __builtin_amdgcn_mfma_f32_32x32x16_f16(a0h[KS], B##2, acc00, 0,0,0); \
    acc01 = __builtin_amdgcn_mfma_f32_32x32x16_f16(a0h[KS], B##3, acc01, 0,0,0); \
    acc10 = __builtin_amdgcn_mfma_f32_32x32x16_f16(a1h[KS], B##2, acc10, 0,0,0); \
    acc11 = __builtin_amdgcn_mfma_f32_32x32x16_f16(a1h[KS], B##3, acc11, 0,0,0); \
    acc00 = __builtin_amdgcn_mfma_f32_32x32x16_f16(a0l[KS], B##0, acc00, 0,0,0); \
    acc01 = __builtin_amdgcn_mfma_f32_32x32x16_f16(a0l[KS], B##1, acc01, 0,0,0); \
    acc10 = __builtin_amdgcn_mfma_f32_32x32x16_f16(a1l[KS], B##0, acc10, 0,0,0); \
    acc11 = __builtin_amdgcn_mfma_f32_32x32x16_f16(a1l[KS], B##1, acc11, 0,0,0);

#define STEP(KS, CUR, NXT, LAST)                                             \
    { if (!(LAST)) PRIME((KS) + 1, NXT)                                      \
      MFMA12((KS), CUR) }

    #pragma unroll 1
    for (int jt = 0; jt < JTS; ++jt) {
        const int buf = jt & 1;
        const int jb  = jq + jt * JT;

        // prefetch next jt's B into the other buffer (drained at barrier)
        if (jt + 1 < JTS) dmaB(buf ^ 1, jt + 1);

        // cbsq for this jt (in flight over the whole jt)
        const float csq0 = cbsq[jb + lr32];
        const float csq1 = cbsq[jb + 32 + lr32];

        const char* bbase = smB + buf * 65536 + lslot;
        half8_t p0, p1, p2, p3, q0, q1, q2, q3;

        PRIME(0, p)
        STEP(0,  p, q, 0) STEP(1,  q, p, 0)
        STEP(2,  p, q, 0) STEP(3,  q, p, 0)
        STEP(4,  p, q, 0) STEP(5,  q, p, 0)
        STEP(6,  p, q, 0) STEP(7,  q, p, 0)
        STEP(8,  p, q, 0) STEP(9,  q, p, 0)
        STEP(10, p, q, 0) STEP(11, q, p, 0)
        STEP(12, p, q, 0) STEP(13, q, p, 0)
        STEP(14, p, q, 0) STEP(15, q, p, 1)

        // ---- fold: d2 = cbsq - 2*dot. C layout (validated):
        // col = jb + n*32 + lr32, row = m*32 + (r&3) + 8*(r>>2) + 4*kh.
        #pragma unroll
        for (int r = 0; r < 16; ++r) {
            {
                float s0 = csq0 - 2.0f * acc00[r];
                float s1 = csq1 - 2.0f * acc01[r];
                float sv = s0; int si = jb + lr32;
                if (s1 < sv) { sv = s1; si = jb + 32 + lr32; }
                if (sv < minv[r]) { minv[r] = sv; mini[r] = si; }
                acc00[r] = 0.f; acc01[r] = 0.f;
            }
            {
                float s0 = csq0 - 2.0f * acc10[r];
                float s1 = csq1 - 2.0f * acc11[r];
                float sv = s0; int si = jb + lr32;
                if (s1 < sv) { sv = s1; si = jb + 32 + lr32; }
                if (sv < minv[16 + r]) { minv[16 + r] = sv; mini[16 + r] = si; }
                acc10[r] = 0.f; acc11[r] = 0.f;
            }
        }

        // jt rendezvous: drains my DMA + all waves' reads of buf
        __syncthreads();
    }
#undef STEP
#undef MFMA12
#undef PRIME

    // ---- epilogue: reduce over the 32 codes held across lanes (lr32),
    // then atomicMin into packed (cross-code-half merge).
    #pragma unroll
    for (int e = 0; e < 32; ++e) {
        float v = minv[e];
        int   x = mini[e];
        #pragma unroll
        for (int m = 1; m <= 16; m <<= 1) {
            float ov = __shfl_xor(v, m, 64);
            int   ox = __shfl_xor(x, m, 64);
            if (ov < v || (ov == v && ox < x)) { v = ov; x = ox; }
        }
        if (lr32 == 0) {    // lanes 0 (kh=0) and 32 (kh=1)
            const int m = e >> 4, r = e & 15;
            int tok = n0w + m * 32 + (r & 3) + 8 * (r >> 2) + 4 * kh;
            unsigned sb = __float_as_uint(v);
            sb = (sb & 0x80000000u) ? ~sb : (sb | 0x80000000u);
            unsigned long long key =
                ((unsigned long long)sb << 32) | (unsigned)x;
            atomicMin(&packed[tok], key);
        }
    }
}

// ---------------------------------------------------------------------------
// Kernel 3: gather + straight-through + loss partials + histogram
// ---------------------------------------------------------------------------
__global__ void k_gather(const float* __restrict__ emb,
                         const float* __restrict__ ces,
                         const float* __restrict__ usage,
                         const unsigned long long* __restrict__ packed,
                         float* __restrict__ out_eq,
                         float* __restrict__ codes_f,
                         int* __restrict__ hist,
                         float* __restrict__ partials) {
    int t = threadIdx.x;
    int wave = t >> 6, lane = t & 63;
    int n = blockIdx.x * 4 + wave;
    int k = (int)(packed[n] & 0xFFFFFFFFull);
    float uc = fmaxf(usage[k], 1e-5f);
    int c = lane * 4;

    float4 e = *(const float4*)&emb[(size_t)n * CH + c];
    float4 v = *(const float4*)&ces[(size_t)k * CH + c];
    float ea[4] = {e.x, e.y, e.z, e.w};
    float va[4] = {v.x, v.y, v.z, v.w};
    float eqa[4];
    float p = 0.0f;
    #pragma unroll
    for (int q = 0; q < 4; ++q) {
        float cb = va[q] / uc;
        float eq = ea[q] + (cb - ea[q]);
        eqa[q] = eq;
        float d = eq - ea[q];
        p += d * d;
    }
    *(float4*)&out_eq[(size_t)n * CH + c] =
        (float4){eqa[0], eqa[1], eqa[2], eqa[3]};

    #pragma unroll
    for (int off = 32; off; off >>= 1) p += __shfl_down(p, off);
    __shared__ float ps[4];
    if (lane == 0) {
        ps[wave] = p;
        codes_f[n] = (float)k;
        atomicAdd(&hist[k], 1);
    }
    __syncthreads();
    if (t == 0) partials[blockIdx.x] = ps[0] + ps[1] + ps[2] + ps[3];
}

// ---------------------------------------------------------------------------
// Kernel 4: exclusive prefix sum over hist -> offs, cursor (1 block)
// ---------------------------------------------------------------------------
__global__ void k_scan(const int* __restrict__ hist,
                       int* __restrict__ offs,
                       int* __restrict__ cursor) {
    __shared__ int bs[256];
    int t = threadIdx.x;
    int base = t * 32;
    int loc[32];
    int s = 0;
    #pragma unroll
    for (int i = 0; i < 32; ++i) { loc[i] = s; s += hist[base + i]; }
    int mysum = s;
    bs[t] = s;
    __syncthreads();
    for (int off = 1; off < 256; off <<= 1) {
        int v = (t >= off) ? bs[t - off] : 0;
        __syncthreads();
        bs[t] += v;
        __syncthreads();
    }
    int excl = bs[t] - mysum;
    #pragma unroll
    for (int i = 0; i < 32; ++i) {
        int o = excl + loc[i];
        offs[base + i]   = o;
        cursor[base + i] = o;
    }
}

// ---------------------------------------------------------------------------
// Kernel 5: scatter token ids into code-sorted buckets
// ---------------------------------------------------------------------------
__global__ void k_scatter(const unsigned long long* __restrict__ packed,
                          int* __restrict__ cursor,
                          int* __restrict__ bucket) {
    int n = blockIdx.x * 256 + threadIdx.x;
    int k = (int)(packed[n] & 0xFFFFFFFFull);
    int pos = atomicAdd(&cursor[k], 1);
    bucket[pos] = n;
}

// ---------------------------------------------------------------------------
// Kernel 6: per-code EMA (one BLOCK per code: coalesced 1KB row loads,
// thread t owns channel t, no atomics, no wave-serial latency chain)
// ---------------------------------------------------------------------------
__global__ void k_ema(const float* __restrict__ emb,
                      const float* __restrict__ ces,
                      const float* __restrict__ usage,
                      const int* __restrict__ hist,
                      const int* __restrict__ offs,
                      const int* __restrict__ bucket,
                      float* __restrict__ out_ces,
                      float* __restrict__ out_usage) {
    const float s = 0.01f;
    const float oms = 1.0f - s;
    int k = blockIdx.x, t = threadIdx.x;
    int start = offs[k], cnt = hist[k];
    float sum = 0.0f;
    #pragma unroll 2
    for (int i = 0; i < cnt; ++i) {
        int n = bucket[start + i];            // block-uniform (scalar) load
        sum += emb[(size_t)n * CH + t];       // coalesced row
    }
    out_ces[(size_t)k * CH + t] = oms * ces[(size_t)k * CH + t] + s * sum;
    if (t == 0) out_usage[k] = oms * usage[k] + s * (float)cnt;
}

// ---------------------------------------------------------------------------
// Kernel 7: reduce loss partials, mean over 2^23 elements
// ---------------------------------------------------------------------------
__global__ void k_final(const float* __restrict__ partials,
                        float* __restrict__ out_loss) {
    int t = threadIdx.x;
    float p = 0.0f;
    for (int i = t; i < NT / 4; i += 256) p += partials[i];
    #pragma unroll
    for (int off = 32; off; off >>= 1) p += __shfl_down(p, off);
    __shared__ float ps[4];
    if ((t & 63) == 0) ps[t >> 6] = p;
    __syncthreads();
    if (t == 0)
        out_loss[0] = (ps[0] + ps[1] + ps[2] + ps[3]) * (1.0f / 8388608.0f);
}

extern "C" void kernel_launch(void* const* d_in, const int* in_sizes, int n_in,
                              void* d_out, int out_size, void* d_ws, size_t ws_size,
                              hipStream_t stream) {
    const float* emb   = (const float*)d_in[0];  // [32768, 256]
    const float* usage = (const float*)d_in[1];  // [8192]
    const float* ces   = (const float*)d_in[2];  // [8192, 256]

    float* out      = (float*)d_out;
    float* o_codes  = out;                       // 32768
    float* o_eq     = out + NT;                  // 8388608
    float* o_loss   = o_eq + (size_t)NT * CH;    // 1
    float* o_usage  = o_loss + 1;                // 8192
    float* o_ces    = o_usage + KC;              // 2097152

    unsigned long long* packed = (unsigned long long*)d_ws;   // NT u64
    float* cbsq     = (float*)(packed + NT);                  // KC
    float* partials = cbsq + KC;                              // NT/4
    int* hist   = (int*)(partials + NT / 4);                  // KC
    int* offs   = hist + KC;                                  // KC
    int* cursor = offs + KC;                                  // KC
    int* bucket = cursor + KC;                                // NT
    _Float16* eh  = (_Float16*)(bucket + NT);                 // NT*CH
    _Float16* el  = eh + (size_t)NT * CH;
    _Float16* cbh = el + (size_t)NT * CH;                     // KC*CH
    _Float16* cbl = cbh + (size_t)KC * CH;

    k_prep<<<KC + NT * CH / 1024, 256, 0, stream>>>(
        usage, ces, emb, cbh, cbl, cbsq, eh, el, hist, packed);
    dim3 agrid(NT / 256, 2);
    k_argmin<<<agrid, 256, 0, stream>>>(eh, el, cbh, cbl, cbsq, packed);
    k_gather<<<NT / 4, 256, 0, stream>>>(emb, ces, usage, packed, o_eq,
                                         o_codes, hist, partials);
    k_scan<<<1, 256, 0, stream>>>(hist, offs, cursor);
    k_scatter<<<NT / 256, 256, 0, stream>>>(packed, cursor, bucket);
    k_ema<<<KC, 256, 0, stream>>>(emb, ces, usage, hist, offs, bucket,
                                  o_ces, o_usage);
    k_final<<<1, 256, 0, stream>>>(partials, o_loss);
}